// Round 1
// baseline (2872.733 us; speedup 1.0000x reference)
//
#include <hip/hip_runtime.h>
#include <stdint.h>

#define T_STEPS 14
#define B_DIM   4096
#define I_DIM   2048
#define H_DIM   1024
#define O_DIM   128
#define K_TOT   3072   // I_DIM + H_DIM

typedef __bf16  bf16x8  __attribute__((ext_vector_type(8)));
typedef float   floatx4 __attribute__((ext_vector_type(4)));

__device__ __forceinline__ uint16_t f2bf_rne(float f) {
    uint32_t u = __float_as_uint(f);
    u += 0x7fffu + ((u >> 16) & 1u);
    return (uint16_t)(u >> 16);
}
__device__ __forceinline__ float bf2f(uint16_t h) {
    return __uint_as_float(((uint32_t)h) << 16);
}

// async global->LDS, 16B per lane; lds ptr must be wave-uniform base (dest = base + lane*16)
__device__ __forceinline__ void gload_lds16(const uint16_t* g, uint16_t* l) {
    __builtin_amdgcn_global_load_lds((__attribute__((address_space(1))) void*)g,
                                     (__attribute__((address_space(3))) void*)l, 16, 0, 0);
}

// ---------- weight split: w -> bf16 hi/mid/lo, W3[s][h][k], k = [w_in | w_rec] ----------
__global__ void split_w_kernel(const float* __restrict__ w_in, const float* __restrict__ w_rec,
                               uint16_t* __restrict__ W3) {
    int idx = blockIdx.x * 256 + threadIdx.x;          // over H_DIM*K_TOT
    int h = idx / K_TOT;
    int k = idx - h * K_TOT;
    float w = (k < I_DIM) ? w_in[(size_t)h * I_DIM + k]
                          : w_rec[(size_t)h * H_DIM + (k - I_DIM)];
    uint16_t hi = f2bf_rne(w);
    float r1 = w - bf2f(hi);
    uint16_t mid = f2bf_rne(r1);
    float r2 = r1 - bf2f(mid);
    uint16_t lo = f2bf_rne(r2);
    const size_t S = (size_t)H_DIM * K_TOT;
    W3[idx] = hi; W3[idx + S] = mid; W3[idx + 2 * S] = lo;
}

__global__ void split_ow_kernel(const float* __restrict__ out_w, uint16_t* __restrict__ OW3) {
    int idx = blockIdx.x * 256 + threadIdx.x;          // over O_DIM*H_DIM
    float w = out_w[idx];
    uint16_t hi = f2bf_rne(w);
    float r1 = w - bf2f(hi);
    uint16_t mid = f2bf_rne(r1);
    float r2 = r1 - bf2f(mid);
    uint16_t lo = f2bf_rne(r2);
    const size_t S = (size_t)O_DIM * H_DIM;
    OW3[idx] = hi; OW3[idx + S] = mid; OW3[idx + 2 * S] = lo;
}

// ---------- x_t fp32 -> bf16 (values are exactly 0.0/1.0, conversion exact) ----------
__global__ void cvt_x_kernel(const float* __restrict__ xt, uint16_t* __restrict__ xb) {
    int idx = blockIdx.x * 256 + threadIdx.x;          // over B_DIM*I_DIM/4
    float4 v = ((const float4*)xt)[idx];
    ushort4 o;
    o.x = f2bf_rne(v.x); o.y = f2bf_rne(v.y); o.z = f2bf_rne(v.z); o.w = f2bf_rne(v.w);
    ((ushort4*)xb)[idx] = o;
}

// ---------- fused step: C = [x_t|z] @ [w_in|w_rec]^T via bf16x3, + LIF update ----------
// tile 128x128, BK=32, 4 waves (2x2 of 64x64), 16x16x32 bf16 MFMA
__launch_bounds__(256)
__global__ void lif_step_kernel(const uint16_t* __restrict__ Xt,   // [B][I_DIM] bf16
                                const uint16_t* __restrict__ Zin,  // [B][H_DIM] bf16
                                const uint16_t* __restrict__ W3,   // [3][H_DIM][K_TOT] bf16
                                float* __restrict__ V, float* __restrict__ I,
                                uint16_t* __restrict__ Zout) {
    __shared__ uint16_t sA[128 * 32];
    __shared__ uint16_t sB[3][128 * 32];

    const int tid  = threadIdx.x;
    const int wave = tid >> 6, lane = tid & 63;
    const int wm = wave >> 1, wn = wave & 1;
    const int quad = lane >> 4, col = lane & 15;

    const int mBase = blockIdx.y * 128;   // batch rows
    const int nBase = blockIdx.x * 128;   // hidden cols

    floatx4 acc[4][4] = {};

    const int sRowA = wave * 16 + (lane >> 2);  // +j*64
    const int sCol  = (lane & 3) * 8;

    for (int kt = 0; kt < K_TOT / 32; ++kt) {
        const uint16_t* srcA; int strideA; int kb;
        if (kt < I_DIM / 32) { srcA = Xt;  strideA = I_DIM; kb = kt * 32; }
        else                 { srcA = Zin; strideA = H_DIM; kb = (kt - I_DIM / 32) * 32; }

        __syncthreads();
#pragma unroll
        for (int j = 0; j < 2; ++j) {
            const uint16_t* g = srcA + (size_t)(mBase + j * 64 + sRowA) * strideA + kb + sCol;
            gload_lds16(g, &sA[(j * 64 + wave * 16) * 32]);
        }
        const int kbB = kt * 32;
#pragma unroll
        for (int s = 0; s < 3; ++s) {
            const uint16_t* wsrc = W3 + (size_t)s * H_DIM * K_TOT;
#pragma unroll
            for (int j = 0; j < 2; ++j) {
                const uint16_t* g = wsrc + (size_t)(nBase + j * 64 + sRowA) * K_TOT + kbB + sCol;
                gload_lds16(g, &sB[s][(j * 64 + wave * 16) * 32]);
            }
        }
        __syncthreads();

        bf16x8 aF[4];
#pragma unroll
        for (int mi = 0; mi < 4; ++mi) {
            int row = wm * 64 + mi * 16 + col;
            aF[mi] = *reinterpret_cast<const bf16x8*>(&sA[row * 32 + quad * 8]);
        }
#pragma unroll
        for (int s = 0; s < 3; ++s) {
            bf16x8 bF[4];
#pragma unroll
            for (int ni = 0; ni < 4; ++ni) {
                int row = wn * 64 + ni * 16 + col;
                bF[ni] = *reinterpret_cast<const bf16x8*>(&sB[s][row * 32 + quad * 8]);
            }
#pragma unroll
            for (int mi = 0; mi < 4; ++mi)
#pragma unroll
                for (int ni = 0; ni < 4; ++ni)
                    acc[mi][ni] = __builtin_amdgcn_mfma_f32_16x16x32_bf16(
                        aF[mi], bF[ni], acc[mi][ni], 0, 0, 0);
        }
    }

    // LIF epilogue — mirror numpy's op order exactly; no FMA contraction
    {
#pragma clang fp contract(off)
#pragma unroll
        for (int mi = 0; mi < 4; ++mi)
#pragma unroll
            for (int ni = 0; ni < 4; ++ni)
#pragma unroll
                for (int r = 0; r < 4; ++r) {
                    int b = mBase + wm * 64 + mi * 16 + quad * 4 + r;
                    int h = nBase + wn * 64 + ni * 16 + col;
                    size_t idx = (size_t)b * H_DIM + h;
                    float cur = acc[mi][ni][r];
                    float v = V[idx], ii = I[idx];
                    float v_dec = v + 0.1f * ((0.0f - v) + ii);   // v + DT*TAU_MEM_INV*((V_LEAK-v)+i)
                    float i_dec = ii - 0.2f * ii;                 // i - DT*TAU_SYN_INV*i
                    float z = (v_dec > 1.0f) ? 1.0f : 0.0f;
                    V[idx] = (1.0f - z) * v_dec + z * 0.0f;
                    I[idx] = i_dec + cur;
                    Zout[idx] = (v_dec > 1.0f) ? (uint16_t)0x3F80 : (uint16_t)0;
                }
    }
}

// ---------- output GEMM: out = z_T @ out_w^T + out_b (bf16x3, N=128 fits one tile) ----------
__launch_bounds__(256)
__global__ void out_gemm_kernel(const uint16_t* __restrict__ Zfin,  // [B][H_DIM] bf16
                                const uint16_t* __restrict__ OW3,   // [3][O_DIM][H_DIM] bf16
                                const float* __restrict__ out_b,
                                float* __restrict__ out) {
    __shared__ uint16_t sA[128 * 32];
    __shared__ uint16_t sB[3][128 * 32];

    const int tid  = threadIdx.x;
    const int wave = tid >> 6, lane = tid & 63;
    const int wm = wave >> 1, wn = wave & 1;
    const int quad = lane >> 4, col = lane & 15;

    const int mBase = blockIdx.x * 128;

    floatx4 acc[4][4] = {};

    const int sRowA = wave * 16 + (lane >> 2);
    const int sCol  = (lane & 3) * 8;

    for (int kt = 0; kt < H_DIM / 32; ++kt) {
        const int kb = kt * 32;
        __syncthreads();
#pragma unroll
        for (int j = 0; j < 2; ++j) {
            const uint16_t* g = Zfin + (size_t)(mBase + j * 64 + sRowA) * H_DIM + kb + sCol;
            gload_lds16(g, &sA[(j * 64 + wave * 16) * 32]);
        }
#pragma unroll
        for (int s = 0; s < 3; ++s) {
            const uint16_t* wsrc = OW3 + (size_t)s * O_DIM * H_DIM;
#pragma unroll
            for (int j = 0; j < 2; ++j) {
                const uint16_t* g = wsrc + (size_t)(j * 64 + sRowA) * H_DIM + kb + sCol;
                gload_lds16(g, &sB[s][(j * 64 + wave * 16) * 32]);
            }
        }
        __syncthreads();

        bf16x8 aF[4];
#pragma unroll
        for (int mi = 0; mi < 4; ++mi) {
            int row = wm * 64 + mi * 16 + col;
            aF[mi] = *reinterpret_cast<const bf16x8*>(&sA[row * 32 + quad * 8]);
        }
#pragma unroll
        for (int s = 0; s < 3; ++s) {
            bf16x8 bF[4];
#pragma unroll
            for (int ni = 0; ni < 4; ++ni) {
                int row = wn * 64 + ni * 16 + col;
                bF[ni] = *reinterpret_cast<const bf16x8*>(&sB[s][row * 32 + quad * 8]);
            }
#pragma unroll
            for (int mi = 0; mi < 4; ++mi)
#pragma unroll
                for (int ni = 0; ni < 4; ++ni)
                    acc[mi][ni] = __builtin_amdgcn_mfma_f32_16x16x32_bf16(
                        aF[mi], bF[ni], acc[mi][ni], 0, 0, 0);
        }
    }

    {
#pragma clang fp contract(off)
#pragma unroll
        for (int mi = 0; mi < 4; ++mi)
#pragma unroll
            for (int ni = 0; ni < 4; ++ni)
#pragma unroll
                for (int r = 0; r < 4; ++r) {
                    int b = mBase + wm * 64 + mi * 16 + quad * 4 + r;
                    int h = wn * 64 + ni * 16 + col;
                    out[(size_t)b * O_DIM + h] = acc[mi][ni][r] + out_b[h];
                }
    }
}

extern "C" void kernel_launch(void* const* d_in, const int* in_sizes, int n_in,
                              void* d_out, int out_size, void* d_ws, size_t ws_size,
                              hipStream_t stream) {
    const float* x     = (const float*)d_in[0];
    const float* w_in  = (const float*)d_in[1];
    const float* w_rec = (const float*)d_in[2];
    const float* out_w = (const float*)d_in[3];
    const float* out_b = (const float*)d_in[4];
    float* out = (float*)d_out;

    char* ws = (char*)d_ws;
    size_t off = 0;
    uint16_t* W3  = (uint16_t*)(ws + off); off += (size_t)3 * H_DIM * K_TOT * 2;
    uint16_t* OW3 = (uint16_t*)(ws + off); off += (size_t)3 * O_DIM * H_DIM * 2;
    uint16_t* Xt  = (uint16_t*)(ws + off); off += (size_t)B_DIM * I_DIM * 2;
    uint16_t* Z0  = (uint16_t*)(ws + off); off += (size_t)B_DIM * H_DIM * 2;
    uint16_t* Z1  = (uint16_t*)(ws + off); off += (size_t)B_DIM * H_DIM * 2;
    float*    V   = (float*)(ws + off);    off += (size_t)B_DIM * H_DIM * 4;
    float*    I   = (float*)(ws + off);    off += (size_t)B_DIM * H_DIM * 4;

    // zero init: Z0 (carry), Z1 (harmless), V, I — one contiguous region
    hipMemsetAsync(Z0, 0, (size_t)B_DIM * H_DIM * (2 + 2 + 4 + 4), stream);

    split_w_kernel<<<(H_DIM * K_TOT) / 256, 256, 0, stream>>>(w_in, w_rec, W3);
    split_ow_kernel<<<(O_DIM * H_DIM) / 256, 256, 0, stream>>>(out_w, OW3);

    uint16_t* zbuf[2] = { Z0, Z1 };
    for (int t = 0; t < T_STEPS; ++t) {
        cvt_x_kernel<<<(B_DIM * I_DIM / 4) / 256, 256, 0, stream>>>(
            x + (size_t)t * B_DIM * I_DIM, Xt);
        dim3 grid(H_DIM / 128, B_DIM / 128);   // x = N-tile (8) -> XCD shares B columns
        lif_step_kernel<<<grid, 256, 0, stream>>>(Xt, zbuf[t & 1], W3, V, I, zbuf[(t + 1) & 1]);
    }
    // T even -> final z in zbuf[0]
    out_gemm_kernel<<<B_DIM / 128, 256, 0, stream>>>(zbuf[0], OW3, out_b, out);
}

// Round 2
// 2172.187 us; speedup vs baseline: 1.3225x; 1.3225x over previous
//
#include <hip/hip_runtime.h>
#include <stdint.h>

#define T_STEPS 14
#define B_DIM   4096
#define I_DIM   2048
#define H_DIM   1024
#define O_DIM   128
#define K_TOT   3072   // I_DIM + H_DIM

// fixed-point scale 2^25: |w|max ~0.16 -> |W| ~5.1M < 8.35M (3-signed-digit range)
#define WSCALE_F 33554432.0f

typedef __bf16  bf16x8  __attribute__((ext_vector_type(8)));
typedef float   floatx4 __attribute__((ext_vector_type(4)));
typedef int     int4v   __attribute__((ext_vector_type(4)));

__device__ __forceinline__ uint16_t f2bf_rne(float f) {
    uint32_t u = __float_as_uint(f);
    u += 0x7fffu + ((u >> 16) & 1u);
    return (uint16_t)(u >> 16);
}
__device__ __forceinline__ float bf2f(uint16_t h) {
    return __uint_as_float(((uint32_t)h) << 16);
}

// async global->LDS, 16B per lane; LDS dest = wave-uniform base + lane*16
__device__ __forceinline__ void gload_lds16(const void* g, void* l) {
    __builtin_amdgcn_global_load_lds((__attribute__((address_space(1))) void*)g,
                                     (__attribute__((address_space(3))) void*)l, 16, 0, 0);
}

// ---------- weight quantize+split: w -> 3 signed i8 base-256 digits of round(w*2^25) ----------
// W3[s][h][k], k = [w_in | w_rec] ; s=0 low digit (x1), s=1 (x256), s=2 (x65536)
__global__ void split_w_kernel(const float* __restrict__ w_in, const float* __restrict__ w_rec,
                               int8_t* __restrict__ W3) {
    int idx = blockIdx.x * 256 + threadIdx.x;          // over H_DIM*K_TOT
    int h = idx / K_TOT;
    int k = idx - h * K_TOT;
    float w = (k < I_DIM) ? w_in[(size_t)h * I_DIM + k]
                          : w_rec[(size_t)h * H_DIM + (k - I_DIM)];
    int W  = __float2int_rn(w * WSCALE_F);
    int d0 = (int8_t)(W & 0xFF);
    int r1 = (W - d0) >> 8;
    int d1 = (int8_t)(r1 & 0xFF);
    int d2 = (r1 - d1) >> 8;                           // |d2| <= ~80, fits i8
    const size_t S = (size_t)H_DIM * K_TOT;
    W3[idx] = (int8_t)d0; W3[idx + S] = (int8_t)d1; W3[idx + 2 * S] = (int8_t)d2;
}

// ---------- out_w -> bf16 hi/mid/lo (kept from validated round-1 path) ----------
__global__ void split_ow_kernel(const float* __restrict__ out_w, uint16_t* __restrict__ OW3) {
    int idx = blockIdx.x * 256 + threadIdx.x;          // over O_DIM*H_DIM
    float w = out_w[idx];
    uint16_t hi = f2bf_rne(w);
    float r1 = w - bf2f(hi);
    uint16_t mid = f2bf_rne(r1);
    float r2 = r1 - bf2f(mid);
    uint16_t lo = f2bf_rne(r2);
    const size_t S = (size_t)O_DIM * H_DIM;
    OW3[idx] = hi; OW3[idx + S] = mid; OW3[idx + 2 * S] = lo;
}

// ---------- x_t fp32 -> i8 (values exactly 0.0/1.0) ----------
__global__ void cvt_x_kernel(const float* __restrict__ xt, int8_t* __restrict__ xb) {
    int idx = blockIdx.x * 256 + threadIdx.x;          // over B_DIM*I_DIM/16
    const float4* src = (const float4*)(xt + (size_t)idx * 16);
    union { int8_t b[16]; int4v v; } u;
#pragma unroll
    for (int j = 0; j < 4; ++j) {
        float4 f = src[j];
        u.b[j * 4 + 0] = (int8_t)(f.x > 0.5f);
        u.b[j * 4 + 1] = (int8_t)(f.y > 0.5f);
        u.b[j * 4 + 2] = (int8_t)(f.z > 0.5f);
        u.b[j * 4 + 3] = (int8_t)(f.w > 0.5f);
    }
    ((int4v*)xb)[idx] = u.v;
}

// ---------- z i8 -> bf16 for the (validated) bf16 out-GEMM ----------
__global__ void cvt_z_kernel(const int8_t* __restrict__ z, uint16_t* __restrict__ zb) {
    int idx = blockIdx.x * 256 + threadIdx.x;          // over B_DIM*H_DIM/4
    uint32_t w = ((const uint32_t*)z)[idx];
    ushort4 o;
    o.x = (w & 0x000000FFu) ? 0x3F80 : 0;
    o.y = (w & 0x0000FF00u) ? 0x3F80 : 0;
    o.z = (w & 0x00FF0000u) ? 0x3F80 : 0;
    o.w = (w & 0xFF000000u) ? 0x3F80 : 0;
    ((ushort4*)zb)[idx] = o;
}

// ---------- fused step: cur = [x_t|z] @ [w_in|w_rec]^T exact via i8 digits, + LIF ----------
// tile 128M x 64N, BK=64, 4 waves (2x2 of 64x32), mfma_i32_16x16x64_i8
__launch_bounds__(256)
__global__ void lif_step_kernel(const int8_t* __restrict__ Xt,   // [B][I_DIM]
                                const int8_t* __restrict__ Zin,  // [B][H_DIM]
                                const int8_t* __restrict__ W3,   // [3][H_DIM][K_TOT]
                                float* __restrict__ V, float* __restrict__ I,
                                int8_t* __restrict__ Zout) {
    __shared__ int8_t sA[128 * 64];
    __shared__ int8_t sB[3][64 * 64];

    const int tid  = threadIdx.x;
    const int wave = tid >> 6, lane = tid & 63;
    const int wm = wave >> 1, wn = wave & 1;
    const int quad = lane >> 4, col = lane & 15;

    const int mBase = blockIdx.x * 128;   // 32 m-tiles (batch)
    const int nBase = blockIdx.y * 64;    // 16 n-tiles (hidden)

    int4v acc[3][4][2] = {};

    const int ldRow = lane >> 2;          // 0..15 within a wave's 16 rows
    const int ldCol = (lane & 3) * 16;    // byte col within 64B row

    for (int kt = 0; kt < K_TOT / 64; ++kt) {
        const int8_t* srcA; int strideA, kb;
        if (kt < I_DIM / 64) { srcA = Xt;  strideA = I_DIM; kb = kt * 64; }
        else                 { srcA = Zin; strideA = H_DIM; kb = (kt - I_DIM / 64) * 64; }

        __syncthreads();
        // A: 128 rows x 64B = 8KB, 2 rounds; each wave covers 16 rows/round
#pragma unroll
        for (int j = 0; j < 2; ++j) {
            const int8_t* g = srcA + (size_t)(mBase + j * 64 + wave * 16 + ldRow) * strideA + kb + ldCol;
            gload_lds16(g, &sA[(j * 64 + wave * 16) * 64]);
        }
        // B: 3 digits x (64 rows x 64B = 4KB), 1 round each
        const int kbB = kt * 64;
#pragma unroll
        for (int s = 0; s < 3; ++s) {
            const int8_t* g = W3 + (size_t)s * H_DIM * K_TOT
                            + (size_t)(nBase + wave * 16 + ldRow) * K_TOT + kbB + ldCol;
            gload_lds16(g, &sB[s][(wave * 16) * 64]);
        }
        __syncthreads();

        int4v aF[4];
#pragma unroll
        for (int mi = 0; mi < 4; ++mi)
            aF[mi] = *reinterpret_cast<const int4v*>(&sA[(wm * 64 + mi * 16 + col) * 64 + quad * 16]);
#pragma unroll
        for (int s = 0; s < 3; ++s) {
            int4v bF[2];
#pragma unroll
            for (int ni = 0; ni < 2; ++ni)
                bF[ni] = *reinterpret_cast<const int4v*>(&sB[s][(wn * 32 + ni * 16 + col) * 64 + quad * 16]);
#pragma unroll
            for (int mi = 0; mi < 4; ++mi)
#pragma unroll
                for (int ni = 0; ni < 2; ++ni)
                    acc[s][mi][ni] = __builtin_amdgcn_mfma_i32_16x16x64_i8(
                        aF[mi], bF[ni], acc[s][mi][ni], 0, 0, 0);
        }
    }

    // LIF epilogue — mirror numpy's op order exactly; no FMA contraction in LIF math
#pragma unroll
    for (int mi = 0; mi < 4; ++mi)
#pragma unroll
        for (int ni = 0; ni < 2; ++ni)
#pragma unroll
            for (int r = 0; r < 4; ++r) {
                int b = mBase + wm * 64 + mi * 16 + quad * 4 + r;
                int h = nBase + wn * 32 + ni * 16 + col;
                size_t idx = (size_t)b * H_DIM + h;
                // exact digit combine: counts < 2^24 so float conversion is exact
                float cur = (float)acc[2][mi][ni][r] * (1.0f / 512.0f)
                          + (float)acc[1][mi][ni][r] * (1.0f / 131072.0f)
                          + (float)acc[0][mi][ni][r] * (1.0f / 33554432.0f);
                {
#pragma clang fp contract(off)
                    float v = V[idx], ii = I[idx];
                    float v_dec = v + 0.1f * ((0.0f - v) + ii);   // v + DT*TAU_MEM_INV*((V_LEAK-v)+i)
                    float i_dec = ii - 0.2f * ii;                 // i - DT*TAU_SYN_INV*i
                    float z = (v_dec > 1.0f) ? 1.0f : 0.0f;
                    V[idx] = (1.0f - z) * v_dec + z * 0.0f;
                    I[idx] = i_dec + cur;
                    Zout[idx] = (v_dec > 1.0f) ? (int8_t)1 : (int8_t)0;
                }
            }
}

// ---------- output GEMM: out = z_T @ out_w^T + out_b (bf16x3; validated round 1) ----------
__launch_bounds__(256)
__global__ void out_gemm_kernel(const uint16_t* __restrict__ Zfin,  // [B][H_DIM] bf16
                                const uint16_t* __restrict__ OW3,   // [3][O_DIM][H_DIM] bf16
                                const float* __restrict__ out_b,
                                float* __restrict__ out) {
    __shared__ uint16_t sA[128 * 32];
    __shared__ uint16_t sB[3][128 * 32];

    const int tid  = threadIdx.x;
    const int wave = tid >> 6, lane = tid & 63;
    const int wm = wave >> 1, wn = wave & 1;
    const int quad = lane >> 4, col = lane & 15;

    const int mBase = blockIdx.x * 128;

    floatx4 acc[4][4] = {};

    const int sRowA = wave * 16 + (lane >> 2);
    const int sCol  = (lane & 3) * 8;

    for (int kt = 0; kt < H_DIM / 32; ++kt) {
        const int kb = kt * 32;
        __syncthreads();
#pragma unroll
        for (int j = 0; j < 2; ++j) {
            const uint16_t* g = Zfin + (size_t)(mBase + j * 64 + sRowA) * H_DIM + kb + sCol;
            gload_lds16(g, &sA[(j * 64 + wave * 16) * 32]);
        }
#pragma unroll
        for (int s = 0; s < 3; ++s) {
            const uint16_t* wsrc = OW3 + (size_t)s * O_DIM * H_DIM;
#pragma unroll
            for (int j = 0; j < 2; ++j) {
                const uint16_t* g = wsrc + (size_t)(j * 64 + sRowA) * H_DIM + kb + sCol;
                gload_lds16(g, &sB[s][(j * 64 + wave * 16) * 32]);
            }
        }
        __syncthreads();

        bf16x8 aF[4];
#pragma unroll
        for (int mi = 0; mi < 4; ++mi) {
            int row = wm * 64 + mi * 16 + col;
            aF[mi] = *reinterpret_cast<const bf16x8*>(&sA[row * 32 + quad * 8]);
        }
#pragma unroll
        for (int s = 0; s < 3; ++s) {
            bf16x8 bF[4];
#pragma unroll
            for (int ni = 0; ni < 4; ++ni) {
                int row = wn * 64 + ni * 16 + col;
                bF[ni] = *reinterpret_cast<const bf16x8*>(&sB[s][row * 32 + quad * 8]);
            }
#pragma unroll
            for (int mi = 0; mi < 4; ++mi)
#pragma unroll
                for (int ni = 0; ni < 4; ++ni)
                    acc[mi][ni] = __builtin_amdgcn_mfma_f32_16x16x32_bf16(
                        aF[mi], bF[ni], acc[mi][ni], 0, 0, 0);
        }
    }

    {
#pragma clang fp contract(off)
#pragma unroll
        for (int mi = 0; mi < 4; ++mi)
#pragma unroll
            for (int ni = 0; ni < 4; ++ni)
#pragma unroll
                for (int r = 0; r < 4; ++r) {
                    int b = mBase + wm * 64 + mi * 16 + quad * 4 + r;
                    int h = wn * 64 + ni * 16 + col;
                    out[(size_t)b * O_DIM + h] = acc[mi][ni][r] + out_b[h];
                }
    }
}

extern "C" void kernel_launch(void* const* d_in, const int* in_sizes, int n_in,
                              void* d_out, int out_size, void* d_ws, size_t ws_size,
                              hipStream_t stream) {
    const float* x     = (const float*)d_in[0];
    const float* w_in  = (const float*)d_in[1];
    const float* w_rec = (const float*)d_in[2];
    const float* out_w = (const float*)d_in[3];
    const float* out_b = (const float*)d_in[4];
    float* out = (float*)d_out;

    char* ws = (char*)d_ws;
    size_t off = 0;
    int8_t*   W3  = (int8_t*)(ws + off);   off += (size_t)3 * H_DIM * K_TOT;
    uint16_t* OW3 = (uint16_t*)(ws + off); off += (size_t)3 * O_DIM * H_DIM * 2;
    int8_t*   Xt  = (int8_t*)(ws + off);   off += (size_t)B_DIM * I_DIM;
    uint16_t* Zbf = (uint16_t*)(ws + off); off += (size_t)B_DIM * H_DIM * 2;
    // contiguous zero-init region: Z0, Z1, V, I
    int8_t*   Z0  = (int8_t*)(ws + off);   off += (size_t)B_DIM * H_DIM;
    int8_t*   Z1  = (int8_t*)(ws + off);   off += (size_t)B_DIM * H_DIM;
    float*    V   = (float*)(ws + off);    off += (size_t)B_DIM * H_DIM * 4;
    float*    I   = (float*)(ws + off);    off += (size_t)B_DIM * H_DIM * 4;

    hipMemsetAsync(Z0, 0, (size_t)B_DIM * H_DIM * (1 + 1 + 4 + 4), stream);

    split_w_kernel<<<(H_DIM * K_TOT) / 256, 256, 0, stream>>>(w_in, w_rec, W3);
    split_ow_kernel<<<(O_DIM * H_DIM) / 256, 256, 0, stream>>>(out_w, OW3);

    int8_t* zbuf[2] = { Z0, Z1 };
    for (int t = 0; t < T_STEPS; ++t) {
        cvt_x_kernel<<<(B_DIM * I_DIM / 16) / 256, 256, 0, stream>>>(
            x + (size_t)t * B_DIM * I_DIM, Xt);
        dim3 grid(B_DIM / 128, H_DIM / 64);   // x = m-tile, y = n-tile
        lif_step_kernel<<<grid, 256, 0, stream>>>(Xt, zbuf[t & 1], W3, V, I, zbuf[(t + 1) & 1]);
    }
    // T even -> final z in zbuf[0]
    cvt_z_kernel<<<(B_DIM * H_DIM / 4) / 256, 256, 0, stream>>>(zbuf[0], Zbf);
    out_gemm_kernel<<<B_DIM / 128, 256, 0, stream>>>(Zbf, OW3, out_b, out);
}

// Round 4
// 1542.853 us; speedup vs baseline: 1.8620x; 1.4079x over previous
//
#include <hip/hip_runtime.h>
#include <stdint.h>

#define T_STEPS 14
#define B_DIM   4096
#define I_DIM   2048
#define H_DIM   1024
#define O_DIM   128
#define K_TOT   3072   // I_DIM + H_DIM

// fixed-point scale 2^25: |w|max ~0.16 -> |W| ~5.1M, 3 signed base-256 digits exact
#define WSCALE_F 33554432.0f

typedef __bf16  bf16x8  __attribute__((ext_vector_type(8)));
typedef float   floatx4 __attribute__((ext_vector_type(4)));
typedef int     int4v   __attribute__((ext_vector_type(4)));
typedef int     int16v  __attribute__((ext_vector_type(16)));

__device__ __forceinline__ uint16_t f2bf_rne(float f) {
    uint32_t u = __float_as_uint(f);
    u += 0x7fffu + ((u >> 16) & 1u);
    return (uint16_t)(u >> 16);
}
__device__ __forceinline__ float bf2f(uint16_t h) {
    return __uint_as_float(((uint32_t)h) << 16);
}

// async global->LDS, 16B/lane; LDS dest = wave-uniform base + lane*16 (implicit)
__device__ __forceinline__ void gload_lds16(const void* g, void* l) {
    __builtin_amdgcn_global_load_lds((__attribute__((address_space(1))) void*)g,
                                     (__attribute__((address_space(3))) void*)l, 16, 0, 0);
}

// ---------- weight quantize+split into packed digit layout ----------
// WB[nt(16)][kt(48)][s(3)][row(64)][kcol(64)] int8; k = [w_in | w_rec]
__global__ void split_w_kernel(const float* __restrict__ w_in, const float* __restrict__ w_rec,
                               int8_t* __restrict__ WB) {
    int idx = blockIdx.x * 256 + threadIdx.x;          // over H_DIM*K_TOT
    int h = idx / K_TOT;
    int k = idx - h * K_TOT;
    float w = (k < I_DIM) ? w_in[(size_t)h * I_DIM + k]
                          : w_rec[(size_t)h * H_DIM + (k - I_DIM)];
    int W  = __float2int_rn(w * WSCALE_F);
    int d0 = (int8_t)(W & 0xFF);
    int r1 = (W - d0) >> 8;
    int d1 = (int8_t)(r1 & 0xFF);
    int d2 = (r1 - d1) >> 8;                           // |d2| <= ~80
    int nt = h >> 6, row = h & 63, kt = k >> 6, kc = k & 63;
    size_t base = ((size_t)(nt * 48 + kt) * 3) * 4096 + row * 64 + kc;
    WB[base] = (int8_t)d0; WB[base + 4096] = (int8_t)d1; WB[base + 8192] = (int8_t)d2;
}

// ---------- out_w -> bf16 hi/mid/lo (validated) ----------
__global__ void split_ow_kernel(const float* __restrict__ out_w, uint16_t* __restrict__ OW3) {
    int idx = blockIdx.x * 256 + threadIdx.x;          // over O_DIM*H_DIM
    float w = out_w[idx];
    uint16_t hi = f2bf_rne(w);
    float r1 = w - bf2f(hi);
    uint16_t mid = f2bf_rne(r1);
    float r2 = r1 - bf2f(mid);
    uint16_t lo = f2bf_rne(r2);
    const size_t S = (size_t)O_DIM * H_DIM;
    OW3[idx] = hi; OW3[idx + S] = mid; OW3[idx + 2 * S] = lo;
}

// ---------- x fp32 -> i8 for ALL timesteps ----------
__global__ void cvt_x_kernel(const float* __restrict__ x, int8_t* __restrict__ xb) {
    size_t idx = (size_t)blockIdx.x * 256 + threadIdx.x;   // over T*B*I/16
    const float4* src = (const float4*)(x + idx * 16);
    union { int8_t b[16]; int4v v; } u;
#pragma unroll
    for (int j = 0; j < 4; ++j) {
        float4 f = src[j];
        u.b[j * 4 + 0] = (int8_t)(f.x > 0.5f);
        u.b[j * 4 + 1] = (int8_t)(f.y > 0.5f);
        u.b[j * 4 + 2] = (int8_t)(f.z > 0.5f);
        u.b[j * 4 + 3] = (int8_t)(f.w > 0.5f);
    }
    ((int4v*)xb)[idx] = u.v;
}

// ---------- one LIF step (per-step launch; round-3 body, isolated from coop sync) ----------
// tile 128M x 64N, 4 waves (2x2 of 64x32), mfma_i32_32x32x32_i8, BK=64
__launch_bounds__(256, 2)
__global__ void lif_step_kernel(const int8_t* __restrict__ Xt,   // [B][I_DIM], this step
                                const int8_t* __restrict__ Zin,  // [B][H_DIM]
                                const int8_t* __restrict__ WB,   // packed digits
                                float* __restrict__ V, float* __restrict__ I,
                                int8_t* __restrict__ Zout,
                                uint16_t* __restrict__ Zbf, int t) {
    __shared__ int8_t sA[128 * 64];
    __shared__ int8_t sB[3 * 64 * 64];

    const int tid  = threadIdx.x;
    const int wave = tid >> 6, lane = tid & 63;
    const int wm = wave >> 1, wn = wave & 1;
    const int lane32 = lane & 31, half = lane >> 5;

    // XCD swizzle: consecutive bids vary nt -> XCD j holds nt {j, j+8} (1.2MB weights in L2)
    const int nt = blockIdx.x & 15, mIdx = blockIdx.x >> 4;
    const int mBase = mIdx * 128, nBase = nt * 64;

    const int ldRow = lane >> 2;          // 0..15
    const int ldCol = (lane & 3) * 16;    // 0,16,32,48

    int16v acc[3][2] = {};

    // ---- X phase: k chunks 0..31 over Xt (stride I_DIM) ----
    for (int kt = 0; kt < 32; ++kt) {
        __syncthreads();
#pragma unroll
        for (int j = 0; j < 2; ++j) {
            const int8_t* g = Xt + (size_t)(mBase + j * 64 + wave * 16 + ldRow) * I_DIM
                            + kt * 64 + ldCol;
            gload_lds16(g, &sA[(j * 64 + wave * 16) * 64]);
        }
        const int8_t* bsrc = WB + ((size_t)(nt * 48 + kt) * 3) * 4096 + wave * 3072 + lane * 16;
        int8_t* bdst = &sB[wave * 3072];
        gload_lds16(bsrc,        bdst);
        gload_lds16(bsrc + 1024, bdst + 1024);
        gload_lds16(bsrc + 2048, bdst + 2048);
        __syncthreads();
#pragma unroll
        for (int kk = 0; kk < 2; ++kk) {
            int4v aF0 = *(const int4v*)&sA[(wm * 64 +      lane32) * 64 + kk * 32 + half * 16];
            int4v aF1 = *(const int4v*)&sA[(wm * 64 + 32 + lane32) * 64 + kk * 32 + half * 16];
#pragma unroll
            for (int s = 0; s < 3; ++s) {
                int4v bF = *(const int4v*)&sB[s * 4096 + (wn * 32 + lane32) * 64 + kk * 32 + half * 16];
                acc[s][0] = __builtin_amdgcn_mfma_i32_32x32x32_i8(aF0, bF, acc[s][0], 0, 0, 0);
                acc[s][1] = __builtin_amdgcn_mfma_i32_32x32x32_i8(aF1, bF, acc[s][1], 0, 0, 0);
            }
        }
    }
    // ---- Z phase: k chunks 32..47 over Zin (stride H_DIM); z==0 at t==0 ----
    if (t > 0) {
        for (int kt = 0; kt < 16; ++kt) {
            __syncthreads();
#pragma unroll
            for (int j = 0; j < 2; ++j) {
                const int8_t* g = Zin + (size_t)(mBase + j * 64 + wave * 16 + ldRow) * H_DIM
                                + kt * 64 + ldCol;
                gload_lds16(g, &sA[(j * 64 + wave * 16) * 64]);
            }
            const int8_t* bsrc = WB + ((size_t)(nt * 48 + 32 + kt) * 3) * 4096 + wave * 3072 + lane * 16;
            int8_t* bdst = &sB[wave * 3072];
            gload_lds16(bsrc,        bdst);
            gload_lds16(bsrc + 1024, bdst + 1024);
            gload_lds16(bsrc + 2048, bdst + 2048);
            __syncthreads();
#pragma unroll
            for (int kk = 0; kk < 2; ++kk) {
                int4v aF0 = *(const int4v*)&sA[(wm * 64 +      lane32) * 64 + kk * 32 + half * 16];
                int4v aF1 = *(const int4v*)&sA[(wm * 64 + 32 + lane32) * 64 + kk * 32 + half * 16];
#pragma unroll
                for (int s = 0; s < 3; ++s) {
                    int4v bF = *(const int4v*)&sB[s * 4096 + (wn * 32 + lane32) * 64 + kk * 32 + half * 16];
                    acc[s][0] = __builtin_amdgcn_mfma_i32_32x32x32_i8(aF0, bF, acc[s][0], 0, 0, 0);
                    acc[s][1] = __builtin_amdgcn_mfma_i32_32x32x32_i8(aF1, bF, acc[s][1], 0, 0, 0);
                }
            }
        }
    }

    // ---- LIF epilogue: C/D 32x32 layout col=lane32, row=(r&3)+8*(r>>2)+4*half ----
#pragma unroll
    for (int mi = 0; mi < 2; ++mi)
#pragma unroll
        for (int r = 0; r < 16; ++r) {
            int b = mBase + wm * 64 + mi * 32 + ((r & 3) + 8 * (r >> 2) + 4 * half);
            int h = nBase + wn * 32 + lane32;
            size_t idx = (size_t)b * H_DIM + h;
            // exact digit combine (|counts| < 2^24)
            float cur = (float)acc[2][mi][r] * (1.0f / 512.0f)
                      + (float)acc[1][mi][r] * (1.0f / 131072.0f)
                      + (float)acc[0][mi][r] * (1.0f / 33554432.0f);
            {
#pragma clang fp contract(off)
                float v, ii;
                if (t == 0) { v = 0.0f; ii = 0.0f; }
                else        { v = V[idx]; ii = I[idx]; }
                float v_dec = v + 0.1f * ((0.0f - v) + ii);   // v + DT*TAU_MEM_INV*((V_LEAK-v)+i)
                float i_dec = ii - 0.2f * ii;                 // i - DT*TAU_SYN_INV*i
                bool z = (v_dec > 1.0f);
                V[idx] = z ? 0.0f : v_dec;                    // == (1-z)*v_dec + z*V_RESET exactly
                I[idx] = i_dec + cur;
                if (t == T_STEPS - 1) Zbf[idx] = z ? (uint16_t)0x3F80 : (uint16_t)0;
                else                  Zout[idx] = z ? (int8_t)1 : (int8_t)0;
            }
        }
}

// ---------- output GEMM: out = z_T @ out_w^T + out_b (bf16x3; validated) ----------
__launch_bounds__(256)
__global__ void out_gemm_kernel(const uint16_t* __restrict__ Zfin,  // [B][H_DIM] bf16
                                const uint16_t* __restrict__ OW3,   // [3][O_DIM][H_DIM] bf16
                                const float* __restrict__ out_b,
                                float* __restrict__ out) {
    __shared__ uint16_t sA[128 * 32];
    __shared__ uint16_t sB[3][128 * 32];

    const int tid  = threadIdx.x;
    const int wave = tid >> 6, lane = tid & 63;
    const int wm = wave >> 1, wn = wave & 1;
    const int quad = lane >> 4, col = lane & 15;

    const int mBase = blockIdx.x * 128;

    floatx4 acc[4][4] = {};

    const int sRowA = wave * 16 + (lane >> 2);
    const int sCol  = (lane & 3) * 8;

    for (int kt = 0; kt < H_DIM / 32; ++kt) {
        const int kb = kt * 32;
        __syncthreads();
#pragma unroll
        for (int j = 0; j < 2; ++j) {
            const uint16_t* g = Zfin + (size_t)(mBase + j * 64 + sRowA) * H_DIM + kb + sCol;
            gload_lds16(g, &sA[(j * 64 + wave * 16) * 32]);
        }
#pragma unroll
        for (int s = 0; s < 3; ++s) {
            const uint16_t* wsrc = OW3 + (size_t)s * O_DIM * H_DIM;
#pragma unroll
            for (int j = 0; j < 2; ++j) {
                const uint16_t* g = wsrc + (size_t)(j * 64 + sRowA) * H_DIM + kb + sCol;
                gload_lds16(g, &sB[s][(j * 64 + wave * 16) * 32]);
            }
        }
        __syncthreads();

        bf16x8 aF[4];
#pragma unroll
        for (int mi = 0; mi < 4; ++mi) {
            int row = wm * 64 + mi * 16 + col;
            aF[mi] = *reinterpret_cast<const bf16x8*>(&sA[row * 32 + quad * 8]);
        }
#pragma unroll
        for (int s = 0; s < 3; ++s) {
            bf16x8 bF[4];
#pragma unroll
            for (int ni = 0; ni < 4; ++ni) {
                int row = wn * 64 + ni * 16 + col;
                bF[ni] = *reinterpret_cast<const bf16x8*>(&sB[s][row * 32 + quad * 8]);
            }
#pragma unroll
            for (int mi = 0; mi < 4; ++mi)
#pragma unroll
                for (int ni = 0; ni < 4; ++ni)
                    acc[mi][ni] = __builtin_amdgcn_mfma_f32_16x16x32_bf16(
                        aF[mi], bF[ni], acc[mi][ni], 0, 0, 0);
        }
    }

    {
#pragma clang fp contract(off)
#pragma unroll
        for (int mi = 0; mi < 4; ++mi)
#pragma unroll
            for (int ni = 0; ni < 4; ++ni)
#pragma unroll
                for (int r = 0; r < 4; ++r) {
                    int b = mBase + wm * 64 + mi * 16 + quad * 4 + r;
                    int h = wn * 64 + ni * 16 + col;
                    out[(size_t)b * O_DIM + h] = acc[mi][ni][r] + out_b[h];
                }
    }
}

extern "C" void kernel_launch(void* const* d_in, const int* in_sizes, int n_in,
                              void* d_out, int out_size, void* d_ws, size_t ws_size,
                              hipStream_t stream) {
    const float* x     = (const float*)d_in[0];
    const float* w_in  = (const float*)d_in[1];
    const float* w_rec = (const float*)d_in[2];
    const float* out_w = (const float*)d_in[3];
    const float* out_b = (const float*)d_in[4];
    float* out = (float*)d_out;

    char* ws = (char*)d_ws;
    size_t off = 0;
    int8_t*   WB   = (int8_t*)(ws + off);   off += (size_t)3 * H_DIM * K_TOT;        // 9.4 MB
    uint16_t* OW3  = (uint16_t*)(ws + off); off += (size_t)3 * O_DIM * H_DIM * 2;    // 0.8 MB
    int8_t*   Xall = (int8_t*)(ws + off);   off += (size_t)T_STEPS * B_DIM * I_DIM;  // 117 MB
    uint16_t* Zbf  = (uint16_t*)(ws + off); off += (size_t)B_DIM * H_DIM * 2;        // 8 MB
    int8_t*   Z0   = (int8_t*)(ws + off);   off += (size_t)B_DIM * H_DIM;            // 4 MB
    int8_t*   Z1   = (int8_t*)(ws + off);   off += (size_t)B_DIM * H_DIM;            // 4 MB
    float*    V    = (float*)(ws + off);    off += (size_t)B_DIM * H_DIM * 4;        // 16 MB
    float*    Icur = (float*)(ws + off);    off += (size_t)B_DIM * H_DIM * 4;        // 16 MB

    split_w_kernel<<<(H_DIM * K_TOT) / 256, 256, 0, stream>>>(w_in, w_rec, WB);
    split_ow_kernel<<<(O_DIM * H_DIM) / 256, 256, 0, stream>>>(out_w, OW3);
    cvt_x_kernel<<<(int)(((size_t)T_STEPS * B_DIM * I_DIM / 16) / 256), 256, 0, stream>>>(x, Xall);

    int8_t* zbuf[2] = { Z0, Z1 };
    for (int t = 0; t < T_STEPS; ++t) {
        lif_step_kernel<<<dim3(512), 256, 0, stream>>>(
            Xall + (size_t)t * B_DIM * I_DIM, zbuf[t & 1], WB, V, Icur,
            zbuf[(t + 1) & 1], Zbf, t);
    }
    out_gemm_kernel<<<B_DIM / 128, 256, 0, stream>>>(Zbf, OW3, out_b, out);
}